// Round 5
// baseline (285.151 us; speedup 1.0000x reference)
//
#include <hip/hip_runtime.h>
#include <math.h>

#define NBINS 15
#define NBLK  2048          // 8 blocks/CU on 256 CUs -> fully co-resident
#define WPB   4             // waves per block (256 threads)
#define NWAVES (NBLK * WPB) // 8192 waves -> 4 rows/wave at B=32768

// ---------------------------------------------------------------------------
// Single fused kernel. Main loop is the round-2 proven body, UNCHANGED:
// plain loads (no prefetch -- rounds 1/4 proved prefetch is a non-bottleneck),
// v_max3 tree + value-only butterfly, ballot/SALU argmax (masks live in
// SGPR pairs), exp-sum butterfly, fused soft-bin accumulation.
// Then: block combine -> transposed partials, last block (fence/atomic/fence)
// reduces all partials in DOUBLE, fixed order -> loss. Counter is zeroed by a
// hipMemsetAsync node each launch (poison-safe).
// Round-3's 362us disaster was the register double-buffer payload (spill),
// NOT the fused finalize -- that payload is gone here.
// ---------------------------------------------------------------------------
__global__ __launch_bounds__(256, 8) void fused_calib_kernel(
    const float* __restrict__ logits, const int* __restrict__ labels,
    float* __restrict__ partials, unsigned* __restrict__ counter,
    float* __restrict__ out, int B)
{
    const int lane = threadIdx.x & 63;
    const int wid  = threadIdx.x >> 6;

    // lane -> (stat t, bin j); boundaries match np.linspace: f32(i * (1/15 in double))
    const int   tsel = lane / 15;
    const int   jb   = lane - tsel * 15;
    const float lo   = (float)( jb      * (1.0 / 15.0));
    const float up   = (float)((jb + 1) * (1.0 / 15.0));

    float acc = 0.0f;
    const float NI = -INFINITY;

    for (int row = blockIdx.x * WPB + wid; row < B; row += NWAVES) {
        const float4* rp = reinterpret_cast<const float4*>(logits + (size_t)row * 1000);
        float4 v0 = rp[lane];
        float4 v1 = rp[lane + 64];
        float4 v2 = rp[lane + 128];
        float4 v3 = make_float4(NI, NI, NI, NI);
        if (lane < 58) v3 = rp[lane + 192];
        const int lab = labels[row];

        // ---- lane-local max (value only), v_max3-friendly triples ----
        float t0 = fmaxf(fmaxf(v0.x, v0.y), v0.z);
        float t1 = fmaxf(fmaxf(v0.w, v1.x), v1.y);
        float t2 = fmaxf(fmaxf(v1.z, v1.w), v2.x);
        float t3 = fmaxf(fmaxf(v2.y, v2.z), v2.w);
        float t4 = fmaxf(fmaxf(v3.x, v3.y), v3.z);
        float m  = fmaxf(fmaxf(fmaxf(t0, t1), fmaxf(t2, t3)), fmaxf(t4, v3.w));

        // value-only butterfly: all lanes get row max M
        #pragma unroll
        for (int off = 1; off < 64; off <<= 1)
            m = fmaxf(m, __shfl_xor(m, off, 64));

        // ---- argmax via ballots: wave-uniform SGPR masks, SALU scan ----
        unsigned long long b00 = __ballot(v0.x == m), b01 = __ballot(v0.y == m);
        unsigned long long b02 = __ballot(v0.z == m), b03 = __ballot(v0.w == m);
        unsigned long long b10 = __ballot(v1.x == m), b11 = __ballot(v1.y == m);
        unsigned long long b12 = __ballot(v1.z == m), b13 = __ballot(v1.w == m);
        unsigned long long b20 = __ballot(v2.x == m), b21 = __ballot(v2.y == m);
        unsigned long long b22 = __ballot(v2.z == m), b23 = __ballot(v2.w == m);
        unsigned long long b30 = __ballot(v3.x == m), b31 = __ballot(v3.y == m);
        unsigned long long b32 = __ballot(v3.z == m), b33 = __ballot(v3.w == m);

        int best = 1 << 30;
        {
            // scan k = 3..0, overwrite: final best = first index
            unsigned long long u3 = b30 | b31 | b32 | b33;
            if (u3) {
                int l = __ffsll(u3) - 1;
                int c = ((b30 >> l) & 1) ? 0 : ((b31 >> l) & 1) ? 1 : ((b32 >> l) & 1) ? 2 : 3;
                best = 256 * 3 + 4 * l + c;
            }
            unsigned long long u2 = b20 | b21 | b22 | b23;
            if (u2) {
                int l = __ffsll(u2) - 1;
                int c = ((b20 >> l) & 1) ? 0 : ((b21 >> l) & 1) ? 1 : ((b22 >> l) & 1) ? 2 : 3;
                best = 256 * 2 + 4 * l + c;
            }
            unsigned long long u1 = b10 | b11 | b12 | b13;
            if (u1) {
                int l = __ffsll(u1) - 1;
                int c = ((b10 >> l) & 1) ? 0 : ((b11 >> l) & 1) ? 1 : ((b12 >> l) & 1) ? 2 : 3;
                best = 256 * 1 + 4 * l + c;
            }
            unsigned long long u0 = b00 | b01 | b02 | b03;
            if (u0) {
                int l = __ffsll(u0) - 1;
                int c = ((b00 >> l) & 1) ? 0 : ((b01 >> l) & 1) ? 1 : ((b02 >> l) & 1) ? 2 : 3;
                best = 4 * l + c;
            }
        }
        const float corr = (best == lab) ? 1.0f : 0.0f;

        // ---- sum of exp(l - M); -inf pads contribute exactly 0 ----
        float s = __expf(v0.x - m) + __expf(v0.y - m) + __expf(v0.z - m) + __expf(v0.w - m)
                + __expf(v1.x - m) + __expf(v1.y - m) + __expf(v1.z - m) + __expf(v1.w - m)
                + __expf(v2.x - m) + __expf(v2.y - m) + __expf(v2.z - m) + __expf(v2.w - m)
                + __expf(v3.x - m) + __expf(v3.y - m) + __expf(v3.z - m) + __expf(v3.w - m);
        #pragma unroll
        for (int off = 1; off < 64; off <<= 1) s += __shfl_xor(s, off, 64);

        const float conf = 1.0f / s;   // exp(M-M)=1 over Z

        // ---- fused soft-bin accumulation (lanes 0..44) ----
        if (lane < 45) {
            const float s1 = 1.0f / (1.0f + __expf(-20.0f * (conf - lo)));
            const float s2 = 1.0f / (1.0f + __expf(-20.0f * (up - conf)));
            const float ib = s1 * s2;
            const float wgt = (tsel == 0) ? 1.0f : ((tsel == 1) ? corr : conf);
            acc += ib * wgt;
        }
    }

    // ---- fixed-order block combine -> transposed partials[j][block] ----
    __shared__ float part[WPB][48];
    if (lane < 45) part[wid][lane] = acc;
    __syncthreads();
    const int tid = threadIdx.x;
    if (tid < 45) {
        partials[(size_t)tid * NBLK + blockIdx.x] =
            ((part[0][tid] + part[1][tid]) + part[2][tid]) + part[3][tid];
    }

    // ---- last-block finalize (deterministic, double precision) ----
    __threadfence();                          // release partials
    __shared__ bool isLast;
    if (tid == 0) isLast = (atomicAdd(counter, 1u) == NBLK - 1);
    __syncthreads();
    if (!isLast) return;
    __threadfence();                          // acquire all partials

    // wave w reduces rows j = w, w+4, ... : 8 coalesced float4 per lane,
    // fixed-order double accumulation + fixed-order double butterfly
    // (bit-identical reduction order to the round-2 finalize kernel).
    __shared__ double dsum[45];
    for (int j = wid; j < 45; j += WPB) {
        const float4* fp = reinterpret_cast<const float4*>(partials + (size_t)j * NBLK);
        double s = 0.0;
        #pragma unroll
        for (int t = 0; t < NBLK / 256; ++t) {   // 2048/4 float4 = 512 = 64 lanes x 8
            float4 v = fp[lane + 64 * t];
            s += (double)v.x; s += (double)v.y; s += (double)v.z; s += (double)v.w;
        }
        #pragma unroll
        for (int off = 1; off < 64; off <<= 1) s += __shfl_xor(s, off, 64);
        if (lane == 0) dsum[j] = s;
    }
    __syncthreads();

    __shared__ double term[NBINS];
    if (tid < NBINS) {
        const double mass = dsum[tid];
        const double accd = dsum[NBINS + tid]     / (mass + 1e-8);
        const double cfd  = dsum[2 * NBINS + tid] / (mass + 1e-8);
        const double d    = accd - cfd;
        term[tid] = d * d * mass;
    }
    __syncthreads();

    if (tid == 0) {
        double loss = 0.0;
        for (int i = 0; i < NBINS; ++i) loss += term[i];
        out[0] = (float)(loss / (double)B);
    }
}

// ---------------------------------------------------------------------------
// ws layout: partials[45 * NBLK] f32 (360 KiB, fully rewritten every launch)
//            | counter u32 (zeroed by memset node every launch -> poison-safe)
// ---------------------------------------------------------------------------
extern "C" void kernel_launch(void* const* d_in, const int* in_sizes, int n_in,
                              void* d_out, int out_size, void* d_ws, size_t ws_size,
                              hipStream_t stream)
{
    const float* logits = (const float*)d_in[0];
    const int*   labels = (const int*)d_in[1];
    const int B = in_sizes[1];   // 32768 rows; in_sizes[0]/B == 1000 classes

    float*    partials = (float*)d_ws;
    unsigned* counter  = (unsigned*)(partials + 45 * NBLK);

    hipMemsetAsync(counter, 0, sizeof(unsigned), stream);
    fused_calib_kernel<<<NBLK, 256, 0, stream>>>(logits, labels, partials,
                                                 counter, (float*)d_out, B);
}

// Round 6
// 28.120 us; speedup vs baseline: 10.1405x; 10.1405x over previous
//
#include <hip/hip_runtime.h>
#include <math.h>

#define NBINS 15
#define NBLK  1024          // 4 blocks/CU on 256 CUs (512-thread blocks)
#define WPB   8             // waves per block (512 threads)
#define NWAVES (NBLK * WPB) // 8192 waves -> 4 rows/wave at B=32768

typedef float f4 __attribute__((ext_vector_type(4)));

// ---------------------------------------------------------------------------
// Main kernel: one WAVE per row (grid-stride). Round-2 proven body, with two
// deltas only: (a) 512-thread blocks (same 32 waves/CU occupancy, half the
// blocks -> half the partials), (b) nontemporal streaming loads for the row
// data (read-once, no L2 retention needed).
// NO device-scope fences / atomics anywhere (rounds 3+5: per-block
// __threadfence at >=2048 blocks costs ~350us on gfx950 -- L2 maintenance
// serializes per-XCD and evicts the input from cache).
// ---------------------------------------------------------------------------
__global__ __launch_bounds__(512, 8) void fused_row_bin_kernel(
    const float* __restrict__ logits, const int* __restrict__ labels,
    float* __restrict__ partials, int B)
{
    const int lane = threadIdx.x & 63;
    const int wid  = threadIdx.x >> 6;

    // lane -> (stat t, bin j); boundaries match np.linspace: f32(i * (1/15 in double))
    const int   tsel = lane / 15;
    const int   jb   = lane - tsel * 15;
    const float lo   = (float)( jb      * (1.0 / 15.0));
    const float up   = (float)((jb + 1) * (1.0 / 15.0));

    float acc = 0.0f;
    const float NI = -INFINITY;

    for (int row = blockIdx.x * WPB + wid; row < B; row += NWAVES) {
        const f4* rp = reinterpret_cast<const f4*>(logits + (size_t)row * 1000);
        f4 v0 = __builtin_nontemporal_load(rp + lane);
        f4 v1 = __builtin_nontemporal_load(rp + lane + 64);
        f4 v2 = __builtin_nontemporal_load(rp + lane + 128);
        f4 v3;
        if (lane < 58) v3 = __builtin_nontemporal_load(rp + lane + 192);
        else           v3 = (f4){NI, NI, NI, NI};
        const int lab = labels[row];

        // ---- lane-local max (value only), v_max3-friendly triples ----
        float t0 = fmaxf(fmaxf(v0.x, v0.y), v0.z);
        float t1 = fmaxf(fmaxf(v0.w, v1.x), v1.y);
        float t2 = fmaxf(fmaxf(v1.z, v1.w), v2.x);
        float t3 = fmaxf(fmaxf(v2.y, v2.z), v2.w);
        float t4 = fmaxf(fmaxf(v3.x, v3.y), v3.z);
        float m  = fmaxf(fmaxf(fmaxf(t0, t1), fmaxf(t2, t3)), fmaxf(t4, v3.w));

        // value-only butterfly: all lanes get row max M
        #pragma unroll
        for (int off = 1; off < 64; off <<= 1)
            m = fmaxf(m, __shfl_xor(m, off, 64));

        // ---- argmax via ballots: wave-uniform SGPR masks, SALU scan ----
        unsigned long long b00 = __ballot(v0.x == m), b01 = __ballot(v0.y == m);
        unsigned long long b02 = __ballot(v0.z == m), b03 = __ballot(v0.w == m);
        unsigned long long b10 = __ballot(v1.x == m), b11 = __ballot(v1.y == m);
        unsigned long long b12 = __ballot(v1.z == m), b13 = __ballot(v1.w == m);
        unsigned long long b20 = __ballot(v2.x == m), b21 = __ballot(v2.y == m);
        unsigned long long b22 = __ballot(v2.z == m), b23 = __ballot(v2.w == m);
        unsigned long long b30 = __ballot(v3.x == m), b31 = __ballot(v3.y == m);
        unsigned long long b32 = __ballot(v3.z == m), b33 = __ballot(v3.w == m);

        int best = 1 << 30;
        {
            // scan k = 3..0, overwrite: final best = first index
            unsigned long long u3 = b30 | b31 | b32 | b33;
            if (u3) {
                int l = __ffsll(u3) - 1;
                int c = ((b30 >> l) & 1) ? 0 : ((b31 >> l) & 1) ? 1 : ((b32 >> l) & 1) ? 2 : 3;
                best = 256 * 3 + 4 * l + c;
            }
            unsigned long long u2 = b20 | b21 | b22 | b23;
            if (u2) {
                int l = __ffsll(u2) - 1;
                int c = ((b20 >> l) & 1) ? 0 : ((b21 >> l) & 1) ? 1 : ((b22 >> l) & 1) ? 2 : 3;
                best = 256 * 2 + 4 * l + c;
            }
            unsigned long long u1 = b10 | b11 | b12 | b13;
            if (u1) {
                int l = __ffsll(u1) - 1;
                int c = ((b10 >> l) & 1) ? 0 : ((b11 >> l) & 1) ? 1 : ((b12 >> l) & 1) ? 2 : 3;
                best = 256 * 1 + 4 * l + c;
            }
            unsigned long long u0 = b00 | b01 | b02 | b03;
            if (u0) {
                int l = __ffsll(u0) - 1;
                int c = ((b00 >> l) & 1) ? 0 : ((b01 >> l) & 1) ? 1 : ((b02 >> l) & 1) ? 2 : 3;
                best = 4 * l + c;
            }
        }
        const float corr = (best == lab) ? 1.0f : 0.0f;

        // ---- sum of exp(l - M); -inf pads contribute exactly 0 ----
        float s = __expf(v0.x - m) + __expf(v0.y - m) + __expf(v0.z - m) + __expf(v0.w - m)
                + __expf(v1.x - m) + __expf(v1.y - m) + __expf(v1.z - m) + __expf(v1.w - m)
                + __expf(v2.x - m) + __expf(v2.y - m) + __expf(v2.z - m) + __expf(v2.w - m)
                + __expf(v3.x - m) + __expf(v3.y - m) + __expf(v3.z - m) + __expf(v3.w - m);
        #pragma unroll
        for (int off = 1; off < 64; off <<= 1) s += __shfl_xor(s, off, 64);

        const float conf = 1.0f / s;   // exp(M-M)=1 over Z

        // ---- fused soft-bin accumulation (lanes 0..44) ----
        if (lane < 45) {
            const float s1 = 1.0f / (1.0f + __expf(-20.0f * (conf - lo)));
            const float s2 = 1.0f / (1.0f + __expf(-20.0f * (up - conf)));
            const float ib = s1 * s2;
            const float wgt = (tsel == 0) ? 1.0f : ((tsel == 1) ? corr : conf);
            acc += ib * wgt;
        }
    }

    // ---- fixed-order block combine -> transposed partials[j][block] ----
    __shared__ float part[WPB][48];
    if (lane < 45) part[wid][lane] = acc;
    __syncthreads();
    const int tid = threadIdx.x;
    if (tid < 45) {
        partials[(size_t)tid * NBLK + blockIdx.x] =
            ((((((part[0][tid] + part[1][tid]) + part[2][tid]) + part[3][tid])
               + part[4][tid]) + part[5][tid]) + part[6][tid]) + part[7][tid];
    }
}

// ---------------------------------------------------------------------------
// Finalize: one block, 16 waves. Wave w reduces rows j = w, w+16, w+32 of the
// transposed partials [45][NBLK]: 4 coalesced float4 loads/lane, fixed-order
// double accumulation + fixed-order double butterfly. Deterministic.
// ---------------------------------------------------------------------------
__global__ __launch_bounds__(1024) void finalize_kernel(
    const float* __restrict__ partials, float* __restrict__ out, int B)
{
    const int tid  = threadIdx.x;
    const int lane = tid & 63;
    const int wid  = tid >> 6;           // 16 waves

    __shared__ double dsum[45];
    for (int j = wid; j < 45; j += 16) {
        const float4* fp = reinterpret_cast<const float4*>(partials + (size_t)j * NBLK);
        double s = 0.0;
        #pragma unroll
        for (int t = 0; t < NBLK / 256; ++t) {   // 1024/4 float4 = 256 = 64 lanes x 4
            float4 v = fp[lane + 64 * t];
            s += (double)v.x; s += (double)v.y; s += (double)v.z; s += (double)v.w;
        }
        #pragma unroll
        for (int off = 1; off < 64; off <<= 1) s += __shfl_xor(s, off, 64);
        if (lane == 0) dsum[j] = s;
    }
    __syncthreads();

    __shared__ double term[NBINS];
    if (tid < NBINS) {
        const double mass = dsum[tid];
        const double accd = dsum[NBINS + tid]     / (mass + 1e-8);
        const double cfd  = dsum[2 * NBINS + tid] / (mass + 1e-8);
        const double d    = accd - cfd;
        term[tid] = d * d * mass;
    }
    __syncthreads();

    if (tid == 0) {
        double loss = 0.0;
        for (int i = 0; i < NBINS; ++i) loss += term[i];
        out[0] = (float)(loss / (double)B);
    }
}

// ---------------------------------------------------------------------------
// ws layout: partials[45 * NBLK] f32 = 180 KiB (fully overwritten every
// launch; no counters, no atomics, no fences -> poison-safe, fence-safe).
// ---------------------------------------------------------------------------
extern "C" void kernel_launch(void* const* d_in, const int* in_sizes, int n_in,
                              void* d_out, int out_size, void* d_ws, size_t ws_size,
                              hipStream_t stream)
{
    const float* logits = (const float*)d_in[0];
    const int*   labels = (const int*)d_in[1];
    const int B = in_sizes[1];   // 32768 rows; in_sizes[0]/B == 1000 classes

    float* partials = (float*)d_ws;

    fused_row_bin_kernel<<<NBLK, 512, 0, stream>>>(logits, labels, partials, B);
    finalize_kernel<<<1, 1024, 0, stream>>>(partials, (float*)d_out, B);
}

// Round 7
// 27.958 us; speedup vs baseline: 10.1992x; 1.0058x over previous
//
#include <hip/hip_runtime.h>
#include <math.h>

#define NBINS 15
#define NBLK  512           // 2 blocks/CU on 256 CUs (1024-thread blocks)
#define WPB   16            // waves per block (1024 threads)
#define NWAVES (NBLK * WPB) // 8192 waves -> 4 rows/wave at B=32768

typedef float f4 __attribute__((ext_vector_type(4)));

// ---------------------------------------------------------------------------
// Main kernel: one WAVE per row (grid-stride). Round-6 proven body, only the
// block shape changes (1024 threads / 16 waves): same 8192 waves, same
// 32 waves/CU, but NBLK halves -> partials 90KB (halved finalize traffic).
// NO device-scope fences / grid sync anywhere (rounds 3/5: per-block
// L2-maintenance fences cost ~1.4us each serialized per XCD).
// ---------------------------------------------------------------------------
__global__ __launch_bounds__(1024, 2) void fused_row_bin_kernel(
    const float* __restrict__ logits, const int* __restrict__ labels,
    float* __restrict__ partials, int B)
{
    const int lane = threadIdx.x & 63;
    const int wid  = threadIdx.x >> 6;

    // lane -> (stat t, bin j); boundaries match np.linspace: f32(i * (1/15 in double))
    const int   tsel = lane / 15;
    const int   jb   = lane - tsel * 15;
    const float lo   = (float)( jb      * (1.0 / 15.0));
    const float up   = (float)((jb + 1) * (1.0 / 15.0));

    float acc = 0.0f;
    const float NI = -INFINITY;

    for (int row = blockIdx.x * WPB + wid; row < B; row += NWAVES) {
        const f4* rp = reinterpret_cast<const f4*>(logits + (size_t)row * 1000);
        f4 v0 = __builtin_nontemporal_load(rp + lane);
        f4 v1 = __builtin_nontemporal_load(rp + lane + 64);
        f4 v2 = __builtin_nontemporal_load(rp + lane + 128);
        f4 v3;
        if (lane < 58) v3 = __builtin_nontemporal_load(rp + lane + 192);
        else           v3 = (f4){NI, NI, NI, NI};
        const int lab = labels[row];

        // ---- lane-local max (value only), v_max3-friendly triples ----
        float t0 = fmaxf(fmaxf(v0.x, v0.y), v0.z);
        float t1 = fmaxf(fmaxf(v0.w, v1.x), v1.y);
        float t2 = fmaxf(fmaxf(v1.z, v1.w), v2.x);
        float t3 = fmaxf(fmaxf(v2.y, v2.z), v2.w);
        float t4 = fmaxf(fmaxf(v3.x, v3.y), v3.z);
        float m  = fmaxf(fmaxf(fmaxf(t0, t1), fmaxf(t2, t3)), fmaxf(t4, v3.w));

        // value-only butterfly: all lanes get row max M
        #pragma unroll
        for (int off = 1; off < 64; off <<= 1)
            m = fmaxf(m, __shfl_xor(m, off, 64));

        // ---- argmax via ballots: wave-uniform SGPR masks, SALU scan ----
        unsigned long long b00 = __ballot(v0.x == m), b01 = __ballot(v0.y == m);
        unsigned long long b02 = __ballot(v0.z == m), b03 = __ballot(v0.w == m);
        unsigned long long b10 = __ballot(v1.x == m), b11 = __ballot(v1.y == m);
        unsigned long long b12 = __ballot(v1.z == m), b13 = __ballot(v1.w == m);
        unsigned long long b20 = __ballot(v2.x == m), b21 = __ballot(v2.y == m);
        unsigned long long b22 = __ballot(v2.z == m), b23 = __ballot(v2.w == m);
        unsigned long long b30 = __ballot(v3.x == m), b31 = __ballot(v3.y == m);
        unsigned long long b32 = __ballot(v3.z == m), b33 = __ballot(v3.w == m);

        int best = 1 << 30;
        {
            // scan k = 3..0, overwrite: final best = first index
            unsigned long long u3 = b30 | b31 | b32 | b33;
            if (u3) {
                int l = __ffsll(u3) - 1;
                int c = ((b30 >> l) & 1) ? 0 : ((b31 >> l) & 1) ? 1 : ((b32 >> l) & 1) ? 2 : 3;
                best = 256 * 3 + 4 * l + c;
            }
            unsigned long long u2 = b20 | b21 | b22 | b23;
            if (u2) {
                int l = __ffsll(u2) - 1;
                int c = ((b20 >> l) & 1) ? 0 : ((b21 >> l) & 1) ? 1 : ((b22 >> l) & 1) ? 2 : 3;
                best = 256 * 2 + 4 * l + c;
            }
            unsigned long long u1 = b10 | b11 | b12 | b13;
            if (u1) {
                int l = __ffsll(u1) - 1;
                int c = ((b10 >> l) & 1) ? 0 : ((b11 >> l) & 1) ? 1 : ((b12 >> l) & 1) ? 2 : 3;
                best = 256 * 1 + 4 * l + c;
            }
            unsigned long long u0 = b00 | b01 | b02 | b03;
            if (u0) {
                int l = __ffsll(u0) - 1;
                int c = ((b00 >> l) & 1) ? 0 : ((b01 >> l) & 1) ? 1 : ((b02 >> l) & 1) ? 2 : 3;
                best = 4 * l + c;
            }
        }
        const float corr = (best == lab) ? 1.0f : 0.0f;

        // ---- sum of exp(l - M); -inf pads contribute exactly 0 ----
        float s = __expf(v0.x - m) + __expf(v0.y - m) + __expf(v0.z - m) + __expf(v0.w - m)
                + __expf(v1.x - m) + __expf(v1.y - m) + __expf(v1.z - m) + __expf(v1.w - m)
                + __expf(v2.x - m) + __expf(v2.y - m) + __expf(v2.z - m) + __expf(v2.w - m)
                + __expf(v3.x - m) + __expf(v3.y - m) + __expf(v3.z - m) + __expf(v3.w - m);
        #pragma unroll
        for (int off = 1; off < 64; off <<= 1) s += __shfl_xor(s, off, 64);

        const float conf = 1.0f / s;   // exp(M-M)=1 over Z

        // ---- fused soft-bin accumulation (lanes 0..44) ----
        if (lane < 45) {
            const float s1 = 1.0f / (1.0f + __expf(-20.0f * (conf - lo)));
            const float s2 = 1.0f / (1.0f + __expf(-20.0f * (up - conf)));
            const float ib = s1 * s2;
            const float wgt = (tsel == 0) ? 1.0f : ((tsel == 1) ? corr : conf);
            acc += ib * wgt;
        }
    }

    // ---- fixed-order block combine -> transposed partials[j][block] ----
    __shared__ float part[WPB][48];
    if (lane < 45) part[wid][lane] = acc;
    __syncthreads();
    const int tid = threadIdx.x;
    if (tid < 45) {
        float s = part[0][tid];
        #pragma unroll
        for (int w = 1; w < WPB; ++w) s += part[w][tid];
        partials[(size_t)tid * NBLK + blockIdx.x] = s;
    }
}

// ---------------------------------------------------------------------------
// Finalize: one block, 16 waves. Wave w reduces rows j = w, w+16, w+32 of the
// transposed partials [45][NBLK]: 2 coalesced float4 loads/lane, fixed-order
// double accumulation + fixed-order double butterfly. Deterministic.
// ---------------------------------------------------------------------------
__global__ __launch_bounds__(1024) void finalize_kernel(
    const float* __restrict__ partials, float* __restrict__ out, int B)
{
    const int tid  = threadIdx.x;
    const int lane = tid & 63;
    const int wid  = tid >> 6;           // 16 waves

    __shared__ double dsum[45];
    for (int j = wid; j < 45; j += 16) {
        const float4* fp = reinterpret_cast<const float4*>(partials + (size_t)j * NBLK);
        double s = 0.0;
        #pragma unroll
        for (int t = 0; t < NBLK / 256; ++t) {   // 512/4 float4 = 128 = 64 lanes x 2
            float4 v = fp[lane + 64 * t];
            s += (double)v.x; s += (double)v.y; s += (double)v.z; s += (double)v.w;
        }
        #pragma unroll
        for (int off = 1; off < 64; off <<= 1) s += __shfl_xor(s, off, 64);
        if (lane == 0) dsum[j] = s;
    }
    __syncthreads();

    __shared__ double term[NBINS];
    if (tid < NBINS) {
        const double mass = dsum[tid];
        const double accd = dsum[NBINS + tid]     / (mass + 1e-8);
        const double cfd  = dsum[2 * NBINS + tid] / (mass + 1e-8);
        const double d    = accd - cfd;
        term[tid] = d * d * mass;
    }
    __syncthreads();

    if (tid == 0) {
        double loss = 0.0;
        for (int i = 0; i < NBINS; ++i) loss += term[i];
        out[0] = (float)(loss / (double)B);
    }
}

// ---------------------------------------------------------------------------
// ws layout: partials[45 * NBLK] f32 = 90 KiB (fully overwritten every
// launch; no counters, no atomics, no fences -> poison-safe, fence-safe).
// ---------------------------------------------------------------------------
extern "C" void kernel_launch(void* const* d_in, const int* in_sizes, int n_in,
                              void* d_out, int out_size, void* d_ws, size_t ws_size,
                              hipStream_t stream)
{
    const float* logits = (const float*)d_in[0];
    const int*   labels = (const int*)d_in[1];
    const int B = in_sizes[1];   // 32768 rows; in_sizes[0]/B == 1000 classes

    float* partials = (float*)d_ws;

    fused_row_bin_kernel<<<NBLK, 1024, 0, stream>>>(logits, labels, partials, B);
    finalize_kernel<<<1, 1024, 0, stream>>>(partials, (float*)d_out, B);
}